// Round 5
// baseline (321.686 us; speedup 1.0000x reference)
//
#include <hip/hip_runtime.h>
#include <hip/hip_bf16.h>

constexpr int BATCH = 4;
constexpr int SEQ   = 2048;
constexpr int DIM   = 768;
constexpr int NH    = 12;
constexpr int HDIM  = 64;

typedef __attribute__((ext_vector_type(8))) short bf16x8;
typedef __attribute__((ext_vector_type(4))) float f32x4;
typedef __attribute__((ext_vector_type(4))) short s16x4;

__device__ inline short f2bf(float f) {
    union { float f; unsigned u; } v; v.f = f;
    unsigned r = (v.u + 0x7fff + ((v.u >> 16) & 1)) >> 16;  // RNE
    return (short)r;
}

__device__ inline unsigned pack_bf16x2(float a, float b) {
    union { __hip_bfloat162 h; unsigned u; } c;
    c.h = __float22bfloat162_rn(make_float2(a, b));
    return c.u;
}

__device__ inline float fast_exp2(float x) {
#if __has_builtin(__builtin_amdgcn_exp2f)
    return __builtin_amdgcn_exp2f(x);
#else
    return __expf(x * 0.6931471805599453f);
#endif
}

__device__ inline void gld16(const short* g, short* l) {
    __builtin_amdgcn_global_load_lds(
        (const __attribute__((address_space(1))) void*)g,
        (__attribute__((address_space(3))) void*)l, 16, 0, 0);
}

__device__ inline bool ctx_at(const void* p, bool isU8, int idx) {
    return isU8 ? (((const unsigned char*)p)[idx] != 0)
                : (((const int*)p)[idx] != 0);
}

// ---------------------------------------------------------------------------
// prep: fused fp32->bf16 casts (x, Wq, Wk, Wv, Wo) + mask-layout detect.
// Grid = 6144 (x) + 4*576 (weights) + 1 (detect) blocks of 256.
// ---------------------------------------------------------------------------
__global__ __launch_bounds__(256) void prep_kernel(
    const float* __restrict__ x,  const float* __restrict__ Wq,
    const float* __restrict__ Wk, const float* __restrict__ Wv,
    const float* __restrict__ Wo,
    short* __restrict__ xb,  short* __restrict__ Wqb,
    short* __restrict__ Wkb, short* __restrict__ Wvb,
    short* __restrict__ Wob,
    const unsigned char* __restrict__ ctxm, int ctxbytes, int* __restrict__ flag) {
    const int blk = blockIdx.x;
    constexpr int XBLK = (BATCH * SEQ * DIM / 4) / 256;  // 6144
    constexpr int WBLK = (DIM * DIM / 4) / 256;          // 576

    if (blk == XBLK + 4 * WBLK) {  // detect block
        __shared__ int cnt;
        if (threadIdx.x == 0) cnt = 0;
        __syncthreads();
        int local = 0;
        for (int i = threadIdx.x; i < ctxbytes; i += 256)
            if ((i & 3) != 0 && ctxm[i] != 0) local++;
        atomicAdd(&cnt, local);
        __syncthreads();
        if (threadIdx.x == 0) *flag = (cnt > 0) ? 1 : 0;
        return;
    }

    const float* src; short* dst; int i;
    if (blk < XBLK) {
        src = x; dst = xb;
        i = blk * 256 + threadIdx.x;
    } else {
        const int r = blk - XBLK;
        const int w = r / WBLK;
        src = (w == 0) ? Wq : (w == 1) ? Wk : (w == 2) ? Wv : Wo;
        dst = (w == 0) ? Wqb : (w == 1) ? Wkb : (w == 2) ? Wvb : Wob;
        i = (r - w * WBLK) * 256 + threadIdx.x;
    }
    float4 v = ((const float4*)src)[i];
    s16x4 o;
    o.x = f2bf(v.x); o.y = f2bf(v.y); o.z = f2bf(v.z); o.w = f2bf(v.w);
    ((s16x4*)dst)[i] = o;
}

// ---------------------------------------------------------------------------
// m97-style MFMA GEMM (unchanged).
// ---------------------------------------------------------------------------
template <bool BF16OUT>
__global__ __launch_bounds__(256) void gemm_mfma(
    const short* __restrict__ A,
    const short* __restrict__ W0, const float* __restrict__ bias0, void* __restrict__ C0,
    const short* __restrict__ W1, const float* __restrict__ bias1, void* __restrict__ C1,
    const short* __restrict__ W2, const float* __restrict__ bias2, void* __restrict__ C2,
    float scale0) {
    constexpr int N  = DIM;
    constexpr int Kd = DIM;

    const short* W; const float* bias; void* C; float scale;
    if (blockIdx.z == 0)      { W = W0; bias = bias0; C = C0; scale = scale0; }
    else if (blockIdx.z == 1) { W = W1; bias = bias1; C = C1; scale = 1.f; }
    else                      { W = W2; bias = bias2; C = C2; scale = 1.f; }

    const int tid  = threadIdx.x;
    const int wave = tid >> 6;
    const int lane = tid & 63;
    const int quad = lane >> 4;
    const int l16  = lane & 15;
    const int wm   = wave & 1;
    const int wn   = wave >> 1;
    const int m0   = blockIdx.y * 128;
    const int n0   = blockIdx.x * 128;

    __shared__ short As[128 * 32];
    __shared__ short Bs[128 * 32];

    const int srow = tid >> 2;
    const int skq  = tid & 3;
    const short* Ag = A + (size_t)(m0 + srow) * Kd + skq * 8;
    const short* Wg = W + (size_t)(n0 + srow) * Kd + skq * 8;
    short* AsP = As + srow * 32 + skq * 8;
    short* BsP = Bs + srow * 32 + skq * 8;

    f32x4 acc[4][4] = {};

    for (int kt = 0; kt < Kd; kt += 32) {
        __syncthreads();
        gld16(Ag + kt,                AsP);
        gld16(Ag + kt + 64 * Kd,      AsP + 64 * 32);
        gld16(Wg + kt,                BsP);
        gld16(Wg + kt + 64 * Kd,      BsP + 64 * 32);
        __syncthreads();

        bf16x8 af[4], bfr[4];
#pragma unroll
        for (int mt = 0; mt < 4; ++mt)
            af[mt] = *(const bf16x8*)&As[(wm * 64 + mt * 16 + l16) * 32 + quad * 8];
#pragma unroll
        for (int nt = 0; nt < 4; ++nt)
            bfr[nt] = *(const bf16x8*)&Bs[(wn * 64 + nt * 16 + l16) * 32 + quad * 8];
#pragma unroll
        for (int mt = 0; mt < 4; ++mt)
#pragma unroll
            for (int nt = 0; nt < 4; ++nt)
                acc[mt][nt] = __builtin_amdgcn_mfma_f32_16x16x32_bf16(
                    af[mt], bfr[nt], acc[mt][nt], 0, 0, 0);
    }

    float bv[4];
#pragma unroll
    for (int nt = 0; nt < 4; ++nt) bv[nt] = bias[n0 + wn * 64 + nt * 16 + l16];

#pragma unroll
    for (int mt = 0; mt < 4; ++mt)
#pragma unroll
        for (int nt = 0; nt < 4; ++nt)
#pragma unroll
            for (int reg = 0; reg < 4; ++reg) {
                const int m = m0 + wm * 64 + mt * 16 + quad * 4 + reg;
                const int n = n0 + wn * 64 + nt * 16 + l16;
                const float v = (acc[mt][nt][reg] + bv[nt]) * scale;
                if (BF16OUT) ((short*)C)[(size_t)m * N + n] = f2bf(v);
                else         ((float*)C)[(size_t)m * N + n] = v;
            }
}

// ---------------------------------------------------------------------------
// MFMA flash attention v3.
// Block = (b, h, 64 q rows); 4 waves x 16 q rows; grid 1536 = 6/CU (LDS caps
// at 5/CU = 62% occ). No-max exp2 softmax; masking applied AFTER bf16 pack by
// bitwise AND (comb = ~qctx | packed-key-keep). l computed by MFMA with a
// constant all-ones B fragment (every lane gets its rows' l; no shuffles).
// Key permutation s = 4*l16 + g consistent between P and transposed V.
// ---------------------------------------------------------------------------
__global__ __launch_bounds__(256, 5) void attn_mfma3(
    const short* __restrict__ Qb, const short* __restrict__ Kb,
    const short* __restrict__ Vb, const void* __restrict__ ctxp,
    const int* __restrict__ flagp, short* __restrict__ Ob) {
    const int b    = blockIdx.z;
    const int h    = blockIdx.y;
    const int q0   = blockIdx.x * 64;
    const int tid  = threadIdx.x;
    const int wave = tid >> 6;
    const int lane = tid & 63;
    const int quad = lane >> 4;
    const int l16  = lane & 15;
    const bool isU8 = (*flagp != 0);

    __shared__ short Ks[64][72];       // [key][d]
    __shared__ short Vt[64][72];       // [d][s]
    __shared__ short Ps[4][16][72];    // per-wave P, [q row][s]

    // Q fragments: rows q0 + wave*16 + l16.
    bf16x8 qf[2];
    {
        const short* qp = Qb + (size_t)(b * SEQ + q0 + wave * 16 + l16) * DIM
                        + h * HDIM + quad * 8;
        qf[0] = *(const bf16x8*)qp;
        qf[1] = *(const bf16x8*)(qp + 32);
    }

    // ~qctx per C-row (rows quad*4+reg): 0 for context rows, ~0 for target.
    unsigned nmb[4];
#pragma unroll
    for (int reg = 0; reg < 4; ++reg)
        nmb[reg] = ctx_at(ctxp, isU8, b * SEQ + q0 + wave * 16 + quad * 4 + reg)
                   ? 0u : 0xFFFFFFFFu;

    // Constant all-ones bf16 B fragment for the l-sum MFMA.
    bf16x8 ones;
#pragma unroll
    for (int i = 0; i < 8; ++i) ones[i] = (short)0x3F80;

    f32x4 accl = {};      // l per C-row (same value in every lane of the row)
    f32x4 acc[4] = {};    // O accumulator per d-tile

    for (int t = 0; t < SEQ / 64; ++t) {
        const int k0 = t * 64;
        __syncthreads();
        // Stage K row-major.
        {
            const int key = tid >> 2, d0 = (tid & 3) * 16;
            const uint4* src = (const uint4*)(Kb + (size_t)(b * SEQ + k0 + key) * DIM
                                              + h * HDIM + d0);
            *(uint4*)&Ks[key][d0]     = src[0];
            *(uint4*)&Ks[key][d0 + 8] = src[1];
        }
        // Stage V transposed + s-permuted: Vt[d][4*kl+g] = V[g*16+kl][d].
        {
            const int kl = tid & 15;
            const int d0 = (tid >> 4) * 4;
            s16x4 vr[4];
#pragma unroll
            for (int g = 0; g < 4; ++g)
                vr[g] = *(const s16x4*)(Vb + (size_t)(b * SEQ + k0 + g * 16 + kl) * DIM
                                        + h * HDIM + d0);
#pragma unroll
            for (int i = 0; i < 4; ++i) {
                s16x4 w = {vr[0][i], vr[1][i], vr[2][i], vr[3][i]};
                *(s16x4*)&Vt[d0 + i][4 * kl] = w;
            }
        }
        __syncthreads();

        // Packed key-keep masks for bf16 pairs (g0,g1) and (g2,g3).
        const unsigned long long kmask =
            __ballot(ctx_at(ctxp, isU8, b * SEQ + k0 + lane));
        unsigned km2[2];
#pragma unroll
        for (int gp = 0; gp < 2; ++gp) {
            const unsigned lo = (unsigned)((kmask >> (gp * 32 + l16)) & 1ull);
            const unsigned hi = (unsigned)((kmask >> (gp * 32 + 16 + l16)) & 1ull);
            km2[gp] = (lo ? 0x0000FFFFu : 0u) | (hi ? 0xFFFF0000u : 0u);
        }

        // S = Q @ K^T (log2 domain; 0.125*log2e folded into Q).
        f32x4 s4[4] = {};
#pragma unroll
        for (int ks = 0; ks < 2; ++ks) {
            bf16x8 kf[4];
#pragma unroll
            for (int g = 0; g < 4; ++g)
                kf[g] = *(const bf16x8*)&Ks[g * 16 + l16][ks * 32 + quad * 8];
#pragma unroll
            for (int g = 0; g < 4; ++g)
                s4[g] = __builtin_amdgcn_mfma_f32_16x16x32_bf16(qf[ks], kf[g], s4[g], 0, 0, 0);
        }

        // p = exp2(s); pack to bf16 pairs; mask by AND; write P.
#pragma unroll
        for (int reg = 0; reg < 4; ++reg) {
            const float p0 = fast_exp2(s4[0][reg]);
            const float p1 = fast_exp2(s4[1][reg]);
            const float p2 = fast_exp2(s4[2][reg]);
            const float p3 = fast_exp2(s4[3][reg]);
            uint2 w;
            w.x = pack_bf16x2(p0, p1) & (nmb[reg] | km2[0]);
            w.y = pack_bf16x2(p2, p3) & (nmb[reg] | km2[1]);
            *(uint2*)&Ps[wave][quad * 4 + reg][4 * l16] = w;
        }

        // O += P @ V ; l += P @ 1  (wave-private LDS round-trip for P).
#pragma unroll
        for (int ks = 0; ks < 2; ++ks) {
            bf16x8 pf = *(const bf16x8*)&Ps[wave][l16][ks * 32 + quad * 8];
            accl = __builtin_amdgcn_mfma_f32_16x16x32_bf16(pf, ones, accl, 0, 0, 0);
#pragma unroll
            for (int dt = 0; dt < 4; ++dt) {
                bf16x8 vf = *(const bf16x8*)&Vt[dt * 16 + l16][ks * 32 + quad * 8];
                acc[dt] = __builtin_amdgcn_mfma_f32_16x16x32_bf16(pf, vf, acc[dt], 0, 0, 0);
            }
        }
    }

    float inv[4];
#pragma unroll
    for (int reg = 0; reg < 4; ++reg) inv[reg] = 1.f / accl[reg];
#pragma unroll
    for (int dt = 0; dt < 4; ++dt)
#pragma unroll
        for (int reg = 0; reg < 4; ++reg) {
            const int q = q0 + wave * 16 + quad * 4 + reg;
            Ob[(size_t)(b * SEQ + q) * DIM + h * HDIM + dt * 16 + l16] =
                f2bf(acc[dt][reg] * inv[reg]);
        }
}

// ---------------------------------------------------------------------------
// kernel_launch
// ---------------------------------------------------------------------------
extern "C" void kernel_launch(void* const* d_in, const int* in_sizes, int n_in,
                              void* d_out, int out_size, void* d_ws, size_t ws_size,
                              hipStream_t stream) {
    const float* x   = (const float*)d_in[0];
    const void*  ctx = d_in[1];
    const float* Wq  = (const float*)d_in[2];
    const float* bq  = (const float*)d_in[3];
    const float* Wk  = (const float*)d_in[4];
    const float* bk  = (const float*)d_in[5];
    const float* Wv  = (const float*)d_in[6];
    const float* bv  = (const float*)d_in[7];
    const float* Wo  = (const float*)d_in[8];
    const float* bo  = (const float*)d_in[9];
    float* out = (float*)d_out;

    char* ws = (char*)d_ws;
    int* flag = (int*)ws;
    const size_t bufbf = (size_t)BATCH * SEQ * DIM * sizeof(short);  // 12.6 MB
    const size_t wbuf  = (size_t)DIM * DIM * sizeof(short);          // 1.18 MB
    short* xb  = (short*)(ws + 256);
    short* Qb  = (short*)(ws + 256 + bufbf);
    short* Kb  = (short*)(ws + 256 + 2 * bufbf);
    short* Vb  = (short*)(ws + 256 + 3 * bufbf);
    short* Ab  = (short*)(ws + 256 + 4 * bufbf);
    short* Wqb = (short*)(ws + 256 + 5 * bufbf);
    short* Wkb = (short*)(ws + 256 + 5 * bufbf + wbuf);
    short* Wvb = (short*)(ws + 256 + 5 * bufbf + 2 * wbuf);
    short* Wob = (short*)(ws + 256 + 5 * bufbf + 3 * wbuf);

    constexpr int XBLK = (BATCH * SEQ * DIM / 4) / 256;  // 6144
    constexpr int WBLK = (DIM * DIM / 4) / 256;          // 576
    prep_kernel<<<XBLK + 4 * WBLK + 1, 256, 0, stream>>>(
        x, Wq, Wk, Wv, Wo, xb, Wqb, Wkb, Wvb, Wob,
        (const unsigned char*)ctx, BATCH * SEQ, flag);

    // Q scale = 0.125 * log2(e): scores arrive in exp2 domain.
    dim3 gQKV(DIM / 128, (BATCH * SEQ) / 128, 3);
    gemm_mfma<true><<<gQKV, 256, 0, stream>>>(
        xb, Wqb, bq, Qb, Wkb, bk, Kb, Wvb, bv, Vb, 0.125f * 1.4426950408889634f);

    dim3 gAttn(SEQ / 64, NH, BATCH);
    attn_mfma3<<<gAttn, 256, 0, stream>>>(Qb, Kb, Vb, ctx, flag, Ab);

    dim3 gOut(DIM / 128, (BATCH * SEQ) / 128, 1);
    gemm_mfma<false><<<gOut, 256, 0, stream>>>(
        Ab, Wob, bo, out, Wob, bo, out, Wob, bo, out, 1.f);
}